// Round 7
// baseline (739.026 us; speedup 1.0000x reference)
//
#include <hip/hip_runtime.h>
#include <hip/hip_bf16.h>
#include <stdint.h>

#define NE 128
#define NI 1856
#define NKK 6
#define NH 512
#define NT 4096
#define CAP 320
#define NPAIR (NT*NKK)
#define LD2I (2*NI)

typedef unsigned short u16;
typedef __attribute__((ext_vector_type(4))) float f32x4;
typedef __attribute__((ext_vector_type(8))) short bf16x8;
typedef __attribute__((ext_vector_type(4))) short s16x4;
typedef const void __attribute__((address_space(1)))* gas1p;
typedef void __attribute__((address_space(3)))* gas3p;

#define SFENCE __builtin_amdgcn_sched_barrier(0)

__device__ __forceinline__ short f2bf(float f) {
  union { __hip_bfloat16 h; short s; } c; c.h = __float2bfloat16(f); return c.s;
}
__device__ __forceinline__ float bf2f(short s) {
  union { float f; unsigned u; } v; v.u = ((unsigned)(u16)s) << 16; return v.f;
}

// physical bid -> logical L clustering consecutive L on one XCD (bijective any n)
__device__ __forceinline__ int xcd_logical(int bid, int n) {
  int q = n >> 3, r = n & 7;
  int xcd = bid & 7, j = bid >> 3;
  return xcd * q + (xcd < r ? xcd : r) + j;
}

// ---------------- routing ----------------
__global__ void k_route(const int* __restrict__ topk, int* __restrict__ counts,
                        int* __restrict__ slot_of_pair, int* __restrict__ pair_of_slot) {
  int n = blockIdx.x * 256 + threadIdx.x;
  if (n >= NPAIR) return;
  int e = topk[n];
  int p = atomicAdd(&counts[e], 1);
  int s = (p < CAP) ? e * CAP + p : -1;
  slot_of_pair[n] = s;
  if (s >= 0) pair_of_slot[s] = n;
}

// ---------------- gather: hidden(f32) -> Xbuf(bf16) ----------------
__global__ void k_gather(const float* __restrict__ hid, const int* __restrict__ counts,
                         const int* __restrict__ pair_of_slot, u16* __restrict__ xbuf) {
  int t = threadIdx.x;
  int row = blockIdx.x * 2 + (t >> 7);
  int c = t & 127;
  int e = row / CAP, p = row % CAP;
  if (p >= counts[e]) return;
  int n = pair_of_slot[row];
  int tok = n / NKK;
  f32x4 v = *(const f32x4*)(hid + (size_t)tok * NH + c * 4);
  s16x4 o;
  o[0] = f2bf(v[0]); o[1] = f2bf(v[1]); o[2] = f2bf(v[2]); o[3] = f2bf(v[3]);
  *(s16x4*)(xbuf + (size_t)row * NH + c * 4) = o;
}

// ======================= GEMM1 =======================
// X[<=256,512]bf16 @ Wgu[512, 32gate+32up]f32 -> silu*up -> inter bf16
// 256 thr (4 waves 2Mx2N), BK=32, KT=16. A via glld (4/wave/iter, dbuf 2x16KB);
// B direct-to-register (16 f32 dword/wave/iter, compiler-tracked deps).
// End-of-iter s_waitcnt vmcnt(16): drains A(X+1) glld, keeps B(X+1) in flight.
#define G1_STAGE_A(BUF, KT_) do { \
    char* ad_ = lds + (BUF) * 16384; \
    _Pragma("unroll") \
    for (int i_ = 0; i_ < 4; ++i_) { \
      int seg_ = i_ * 4 + w; \
      int o_ = seg_ * 1024 + l * 16; \
      int r_ = o_ >> 6, slot_ = o_ & 63; \
      int grow_ = base + r_; if (grow_ > CAP - 1) grow_ = CAP - 1; \
      const char* g_ = abase + (size_t)grow_ * (NH * 2) + (size_t)(KT_) * 64 + (slot_ ^ ((r_ & 3) << 4)); \
      __builtin_amdgcn_global_load_lds((gas1p)g_, (gas3p)(ad_ + seg_ * 1024), 16, 0, 0); \
    } } while (0)

#define G1_LOAD_B(DST, KT_) do { \
    const float* pg_ = bsrcg + (size_t)((KT_) * 32 + kg * 8) * LD2I; \
    _Pragma("unroll") \
    for (int j_ = 0; j_ < 8; ++j_) { \
      DST[j_]     = pg_[(size_t)j_ * LD2I]; \
      DST[8 + j_] = pg_[(size_t)j_ * LD2I + NI]; \
    } } while (0)

#define G1_COMPUTE(P, CUR) do { \
    const char* ab_ = lds + (P) * 16384; \
    bf16x8 bg_, bu_; \
    _Pragma("unroll") \
    for (int j_ = 0; j_ < 8; ++j_) { bg_[j_] = f2bf(CUR[j_]); bu_[j_] = f2bf(CUR[8 + j_]); } \
    _Pragma("unroll") \
    for (int mt_ = 0; mt_ < 2; ++mt_) \
      _Pragma("unroll") \
      for (int mf_ = 0; mf_ < 4; ++mf_) { \
        int r_ = mt_ * 128 + wm * 64 + mf_ * 16 + (l & 15); \
        bf16x8 af_ = *(const bf16x8*)(ab_ + r_ * 64 + (kg16 ^ ((r_ & 3) << 4))); \
        acc[mt_][mf_][0] = __builtin_amdgcn_mfma_f32_16x16x32_bf16(af_, bg_, acc[mt_][mf_][0], 0, 0, 0); \
        acc[mt_][mf_][1] = __builtin_amdgcn_mfma_f32_16x16x32_bf16(af_, bu_, acc[mt_][mf_][1], 0, 0, 0); \
      } } while (0)

#define G1_ITER(X, CUR, NXT, BUFC) do { \
    SFENCE; __builtin_amdgcn_s_barrier(); SFENCE; \
    { int nk_ = (X) + 1 < 16 ? (X) + 1 : 15; \
      G1_STAGE_A((BUFC) ^ 1, nk_); SFENCE; G1_LOAD_B(NXT, nk_); } \
    SFENCE; \
    G1_COMPUTE(BUFC, CUR); \
    SFENCE; asm volatile("s_waitcnt vmcnt(16)" ::: "memory"); SFENCE; \
  } while (0)

__global__ __launch_bounds__(256, 3) void k_gemm1(
    const u16* __restrict__ xbuf, const float* __restrict__ wgu,
    const int* __restrict__ counts, u16* __restrict__ inter, int e0, int nblk)
{
  __shared__ __align__(16) char lds[32768];   // A double-buffer 2x16KB; epilogue reuses
  int L = xcd_logical(blockIdx.x, nblk);
  int el = L / 58, nt = L % 58;
  int e = e0 + el;
  int cnt = counts[e]; if (cnt > CAP) cnt = CAP;
  int n0 = nt * 32;
  int t = threadIdx.x, w = t >> 6, l = t & 63;
  int wm = w >> 1, wc = w & 1;
  const char* abase = (const char*)(xbuf + (size_t)e * CAP * NH);

  int kg = l >> 4;                 // k-group 0..3 (8 k each)
  int kg16 = kg * 16;
  int colg = wc * 16 + (l & 15);   // gate col 0..31 (up = +NI)
  const float* bsrcg = wgu + (size_t)e * NH * LD2I + n0 + colg;

  float bva[16], bvb[16];

  for (int base = 0; base < cnt; base += 256) {
    __syncthreads();
    f32x4 acc[2][4][2];
    #pragma unroll
    for (int m = 0; m < 2; ++m)
      #pragma unroll
      for (int f = 0; f < 4; ++f) { acc[m][f][0] = (f32x4){0,0,0,0}; acc[m][f][1] = (f32x4){0,0,0,0}; }

    G1_STAGE_A(0, 0);
    SFENCE;
    G1_LOAD_B(bva, 0);
    SFENCE; asm volatile("s_waitcnt vmcnt(16)" ::: "memory"); SFENCE;

    for (int kt = 0; kt < 16; kt += 2) {
      G1_ITER(kt,     bva, bvb, 0);
      G1_ITER(kt + 1, bvb, bva, 1);
    }
    __syncthreads();   // full drain (incl. trailing clamped loads) before LDS reuse

    // epilogue: silu(g)*u -> repack rows x 64B -> coalesced stores
    int cl = wc * 16 + (l & 15);
    #pragma unroll
    for (int mt = 0; mt < 2; ++mt)
      #pragma unroll
      for (int mf = 0; mf < 4; ++mf) {
        f32x4 g = acc[mt][mf][0], u = acc[mt][mf][1];
        #pragma unroll
        for (int r = 0; r < 4; ++r) {
          float gv = g[r];
          float val = gv / (1.f + __expf(-gv)) * u[r];
          int rl = mt * 128 + wm * 64 + mf * 16 + (l >> 4) * 4 + r;
          *(short*)(lds + rl * 64 + ((cl * 2) ^ ((rl & 3) << 4))) = f2bf(val);
        }
      }
    __syncthreads();
    int rmax = cnt - base; if (rmax > 256) rmax = 256;
    u16* obase = inter + (size_t)(el * CAP + base) * NI + n0;
    #pragma unroll
    for (int i = 0; i < 4; ++i) {
      int task = i * 256 + t;
      int r = task >> 2, p = task & 3;
      if (r < rmax) {
        bf16x8 v = *(const bf16x8*)(lds + r * 64 + ((p * 16) ^ ((r & 3) << 4)));
        *(bf16x8*)(obase + (size_t)r * NI + p * 8) = v;
      }
    }
  }
}

// ======================= GEMM2 =======================
// inter[<=256,1856]bf16 @ Wdn[1856,64]f32 -> Y bf16; KT=58, same pipeline
#define G2_STAGE_A(BUF, KT_) do { \
    char* ad_ = lds + (BUF) * 16384; \
    _Pragma("unroll") \
    for (int i_ = 0; i_ < 4; ++i_) { \
      int seg_ = i_ * 4 + w; \
      int o_ = seg_ * 1024 + l * 16; \
      int r_ = o_ >> 6, slot_ = o_ & 63; \
      int grow_ = base + r_; if (grow_ > CAP - 1) grow_ = CAP - 1; \
      const char* g_ = abase + (size_t)grow_ * (NI * 2) + (size_t)(KT_) * 64 + (slot_ ^ ((r_ & 3) << 4)); \
      __builtin_amdgcn_global_load_lds((gas1p)g_, (gas3p)(ad_ + seg_ * 1024), 16, 0, 0); \
    } } while (0)

#define G2_LOAD_B(DST, KT_) do { \
    const float* pd_ = bsrcd + (size_t)((KT_) * 32 + kg * 8) * NH; \
    _Pragma("unroll") \
    for (int j_ = 0; j_ < 8; ++j_) { \
      DST[j_]     = pd_[(size_t)j_ * NH]; \
      DST[8 + j_] = pd_[(size_t)j_ * NH + 16]; \
    } } while (0)

#define G2_COMPUTE(P, CUR) do { \
    const char* ab_ = lds + (P) * 16384; \
    bf16x8 b0_, b1_; \
    _Pragma("unroll") \
    for (int j_ = 0; j_ < 8; ++j_) { b0_[j_] = f2bf(CUR[j_]); b1_[j_] = f2bf(CUR[8 + j_]); } \
    _Pragma("unroll") \
    for (int mt_ = 0; mt_ < 2; ++mt_) \
      _Pragma("unroll") \
      for (int mf_ = 0; mf_ < 4; ++mf_) { \
        int r_ = mt_ * 128 + wm * 64 + mf_ * 16 + (l & 15); \
        bf16x8 af_ = *(const bf16x8*)(ab_ + r_ * 64 + (kg16 ^ ((r_ & 3) << 4))); \
        acc[mt_][mf_][0] = __builtin_amdgcn_mfma_f32_16x16x32_bf16(af_, b0_, acc[mt_][mf_][0], 0, 0, 0); \
        acc[mt_][mf_][1] = __builtin_amdgcn_mfma_f32_16x16x32_bf16(af_, b1_, acc[mt_][mf_][1], 0, 0, 0); \
      } } while (0)

#define G2_ITER(X, CUR, NXT, BUFC) do { \
    SFENCE; __builtin_amdgcn_s_barrier(); SFENCE; \
    { int nk_ = (X) + 1 < 58 ? (X) + 1 : 57; \
      G2_STAGE_A((BUFC) ^ 1, nk_); SFENCE; G2_LOAD_B(NXT, nk_); } \
    SFENCE; \
    G2_COMPUTE(BUFC, CUR); \
    SFENCE; asm volatile("s_waitcnt vmcnt(16)" ::: "memory"); SFENCE; \
  } while (0)

__global__ __launch_bounds__(256, 3) void k_gemm2(
    const u16* __restrict__ inter, const float* __restrict__ wdn,
    const int* __restrict__ counts, u16* __restrict__ Y, int e0, int nblk)
{
  __shared__ __align__(16) char lds[32768];
  int L = xcd_logical(blockIdx.x, nblk);
  int el = L / 8, nt = L % 8;
  int e = e0 + el;
  int cnt = counts[e]; if (cnt > CAP) cnt = CAP;
  int n0 = nt * 64;
  int t = threadIdx.x, w = t >> 6, l = t & 63;
  int wm = w >> 1, wc = w & 1;
  const char* abase = (const char*)(inter + (size_t)el * CAP * NI);

  int kg = l >> 4;
  int kg16 = kg * 16;
  int col0 = wc * 32 + (l & 15);   // frag0 col; frag1 = +16
  const float* bsrcd = wdn + (size_t)e * NI * NH + n0 + col0;

  float bva[16], bvb[16];

  for (int base = 0; base < cnt; base += 256) {
    __syncthreads();
    f32x4 acc[2][4][2];
    #pragma unroll
    for (int m = 0; m < 2; ++m)
      #pragma unroll
      for (int f = 0; f < 4; ++f) { acc[m][f][0] = (f32x4){0,0,0,0}; acc[m][f][1] = (f32x4){0,0,0,0}; }

    G2_STAGE_A(0, 0);
    SFENCE;
    G2_LOAD_B(bva, 0);
    SFENCE; asm volatile("s_waitcnt vmcnt(16)" ::: "memory"); SFENCE;

    for (int kt = 0; kt < 58; kt += 2) {
      G2_ITER(kt,     bva, bvb, 0);
      G2_ITER(kt + 1, bvb, bva, 1);
    }
    __syncthreads();

    // repack: 256 rows x 128B (64 cols bf16)
    #pragma unroll
    for (int mt = 0; mt < 2; ++mt)
      #pragma unroll
      for (int mf = 0; mf < 4; ++mf)
        #pragma unroll
        for (int f = 0; f < 2; ++f) {
          f32x4 a = acc[mt][mf][f];
          int cl = wc * 32 + f * 16 + (l & 15);
          #pragma unroll
          for (int r = 0; r < 4; ++r) {
            int rl = mt * 128 + wm * 64 + mf * 16 + (l >> 4) * 4 + r;
            *(short*)(lds + rl * 128 + ((cl * 2) ^ ((rl & 7) << 4))) = f2bf(a[r]);
          }
        }
    __syncthreads();
    int rmax = cnt - base; if (rmax > 256) rmax = 256;
    u16* obase = Y + (size_t)(e * CAP + base) * NH + n0;
    #pragma unroll
    for (int i = 0; i < 8; ++i) {
      int task = i * 256 + t;
      int r = task >> 3, p = task & 7;
      if (r < rmax) {
        bf16x8 v = *(const bf16x8*)(lds + r * 128 + ((p * 16) ^ ((r & 7) << 4)));
        *(bf16x8*)(obase + (size_t)r * NH + p * 8) = v;
      }
    }
  }
}

// ---------------- combine ----------------
__global__ void k_combine(const int* __restrict__ slot_of_pair, const float* __restrict__ wts,
                          const u16* __restrict__ Y, float* __restrict__ out)
{
  int t = threadIdx.x;
  int tok = blockIdx.x * 2 + (t >> 7);
  int c = t & 127;
  f32x4 a = (f32x4){0.f, 0.f, 0.f, 0.f};
  #pragma unroll
  for (int k = 0; k < NKK; ++k) {
    int n = tok * NKK + k;
    int s = slot_of_pair[n];
    if (s >= 0) {
      float wv = wts[n];
      s16x4 y = *(const s16x4*)(Y + (size_t)s * NH + c * 4);
      a[0] += wv * bf2f(y[0]);
      a[1] += wv * bf2f(y[1]);
      a[2] += wv * bf2f(y[2]);
      a[3] += wv * bf2f(y[3]);
    }
  }
  *(f32x4*)(out + (size_t)tok * NH + c * 4) = a;
  *(f32x4*)(out + (size_t)(NT + tok) * NH + c * 4) = a;
}

extern "C" void kernel_launch(void* const* d_in, const int* in_sizes, int n_in,
                              void* d_out, int out_size, void* d_ws, size_t ws_size,
                              hipStream_t stream) {
  const float* hid  = (const float*)d_in[0];
  const int*   topk = (const int*)d_in[1];
  const float* wts  = (const float*)d_in[2];
  const float* wgu  = (const float*)d_in[3];
  const float* wdn  = (const float*)d_in[4];

  char* ws = (char*)d_ws;
  size_t off = 0;
  auto alloc = [&](size_t sz) { char* p = ws + off; off = (off + sz + 255) & ~(size_t)255; return p; };
  int* counts        = (int*)alloc(NE * 4);
  int* slot_of_pair  = (int*)alloc((size_t)NPAIR * 4);
  int* pair_of_slot  = (int*)alloc((size_t)NE * CAP * 4);
  u16* xbuf          = (u16*)alloc((size_t)NE * CAP * NH * 2);
  u16* Y             = (u16*)alloc((size_t)NE * CAP * NH * 2);
  size_t remain = ws_size > off ? ws_size - off : 0;
  size_t per_e = (size_t)CAP * NI * 2;
  int chunkE = (int)(remain / per_e);
  if (chunkE > NE) chunkE = NE;
  if (chunkE < 1) chunkE = 1;
  u16* inter = (u16*)(ws + off);

  hipMemsetAsync(counts, 0, NE * 4, stream);
  k_route<<<NPAIR / 256, 256, 0, stream>>>(topk, counts, slot_of_pair, pair_of_slot);
  k_gather<<<NE * CAP / 2, 256, 0, stream>>>(hid, counts, pair_of_slot, xbuf);
  for (int e0 = 0; e0 < NE; e0 += chunkE) {
    int ce = NE - e0 < chunkE ? NE - e0 : chunkE;
    int nb1 = ce * 58;
    int nb2 = ce * 8;
    k_gemm1<<<nb1, 256, 0, stream>>>(xbuf, wgu, counts, inter, e0, nb1);
    k_gemm2<<<nb2, 256, 0, stream>>>(inter, wdn, counts, Y, e0, nb2);
  }
  k_combine<<<NT / 2, 256, 0, stream>>>(slot_of_pair, wts, Y, (float*)d_out);
}